// Round 1
// baseline (699.555 us; speedup 1.0000x reference)
//
#include <hip/hip_runtime.h>
#include <math.h>

#define CDIM 192
#define HWP 9216      // 96*96
#define WIMG 96
#define HIMG 96
#define BDIM 16
#define CONV_N 128

// ---------------- pool: px[b,c,j] = mean over 1024 contiguous floats ----------------
__global__ void pool9_kernel(const float* __restrict__ x, float* __restrict__ px) {
    int blk = blockIdx.x;                          // b*C*9 + c*9 + j
    const float* base = x + (size_t)(blk / 9) * HWP + (size_t)(blk % 9) * 1024;
    float4 v = ((const float4*)base)[threadIdx.x]; // 256 threads * 4 floats = 1024
    float s = v.x + v.y + v.z + v.w;
#pragma unroll
    for (int off = 32; off > 0; off >>= 1) s += __shfl_down(s, off, 64);
    __shared__ float ls[4];
    int wid = threadIdx.x >> 6;
    if ((threadIdx.x & 63) == 0) ls[wid] = s;
    __syncthreads();
    if (threadIdx.x == 0) px[blk] = (ls[0] + ls[1] + ls[2] + ls[3]) * (1.0f / 1024.0f);
}

// ---------------- small: build per-(b,c) 3x3 kernels ----------------
__global__ void make_kernels_kernel(const float* __restrict__ px,
                                    const float* __restrict__ Wk, const float* __restrict__ bk,
                                    const float* __restrict__ Wg, const float* __restrict__ bg,
                                    const float* __restrict__ dc,
                                    float* __restrict__ kk) {
    int b = blockIdx.x;
    int o = threadIdx.x;  // 0..191
    __shared__ float pxs[CDIM * 9];
    for (int i = threadIdx.x; i < CDIM * 9; i += blockDim.x) pxs[i] = px[b * CDIM * 9 + i];
    __syncthreads();
    float k1[9];
    float bias = bk[o];
#pragma unroll
    for (int j = 0; j < 9; j++) k1[j] = bias;
    for (int c = 0; c < CDIM; c++) {
        float w = Wk[o * CDIM + c];
#pragma unroll
        for (int j = 0; j < 9; j++) k1[j] = fmaf(w, pxs[c * 9 + j], k1[j]);
    }
#pragma unroll
    for (int j = 0; j < 9; j++) {
        float v = k1[j];
        k1[j] = 0.5f * v * (1.0f + erff(v * 0.70710678118654752f));  // exact GELU
    }
    float k2[9];
    float mean = 0.f;
#pragma unroll
    for (int i = 0; i < 9; i++) {
        float a = bg[i];
#pragma unroll
        for (int j = 0; j < 9; j++) a = fmaf(k1[j], Wg[i * 9 + j], a);
        k2[i] = a;
        mean += a;
    }
    mean *= (1.0f / 9.0f);
    float f = 1.0f / (1.0f + expf(-dc[o]));
    float sub = f * mean;
#pragma unroll
    for (int i = 0; i < 9; i++) kk[(b * CDIM + o) * 9 + i] = k2[i] - sub;
}

// ---------------- transpose the two 192x192 weight mats: WT[c][o] = W[o][c] ----------------
__global__ void transpose192_kernel(const float* __restrict__ A, const float* __restrict__ Bm,
                                    float* __restrict__ AT, float* __restrict__ BT) {
    int i = blockIdx.x * 256 + threadIdx.x;  // 0 .. 2*36864-1
    int m = i / (CDIM * CDIM);
    int idx = i % (CDIM * CDIM);
    int c = idx / CDIM, o = idx % CDIM;
    const float* src = m ? Bm : A;
    float* dst = m ? BT : AT;
    dst[idx] = src[o * CDIM + c];
}

// ---------------- depthwise 3x3, per-(b,c) kernel, zero pad ----------------
__global__ void dwconv_kernel(const float* __restrict__ xp, const float* __restrict__ kk,
                              float* __restrict__ y) {
    int idx = blockIdx.x * 256 + threadIdx.x;  // over B*C*9216 ; 9216%256==0 -> bc uniform per block
    int bc = idx / HWP;
    int p = idx % HWP;
    int h = p / WIMG, w = p % WIMG;
    const float* base = xp + (size_t)bc * HWP;
    float kv[9];
#pragma unroll
    for (int t = 0; t < 9; t++) kv[t] = kk[bc * 9 + t];
    float s = 0.f;
#pragma unroll
    for (int di = 0; di < 3; di++) {
        int hh = h + di - 1;
        if (hh < 0 || hh >= HIMG) continue;
#pragma unroll
        for (int dj = 0; dj < 3; dj++) {
            int ww = w + dj - 1;
            if (ww < 0 || ww >= WIMG) continue;
            s = fmaf(kv[di * 3 + dj], base[hh * WIMG + ww], s);
        }
    }
    y[idx] = s;
}

// ---------------- conv1x1, K=192, M=192 (all out channels per block), N=128 ----------------
// In-place safe when in==out aliasing at pixel granularity: each block reads ONLY its own
// (b, p0..p0+127) columns (all c) and writes only that range (all o), writes after final barrier.
__global__ __launch_bounds__(256, 2) void conv192_kernel(
    const float* __restrict__ in,   // [B][192][9216]
    const float* __restrict__ WT,   // [192 c][192 o]
    const float* __restrict__ bias, // [192]
    float* __restrict__ out) {      // [B][192][9216]
    int p0 = blockIdx.x * CONV_N;
    int b = blockIdx.y;
    int tid = threadIdx.x;
    int to = tid >> 5;   // 0..7 -> owns o in [to*24, to*24+24)
    int tp = tid & 31;   // 0..31 -> owns p in [p0+tp*4, +4)

    __shared__ float Ws[32][CDIM];    // 24 KB
    __shared__ float Xs[32][CONV_N];  // 16 KB

    float acc[24][4];
#pragma unroll
    for (int m = 0; m < 24; m++) {
        float bv = bias[to * 24 + m];
#pragma unroll
        for (int q = 0; q < 4; q++) acc[m][q] = bv;
    }

    const float* inb = in + (size_t)b * CDIM * HWP;

    for (int ks = 0; ks < 6; ks++) {
        int c0 = ks * 32;
        // stage W chunk: 32x192 floats, coalesced from WT (c-major)
#pragma unroll
        for (int it = 0; it < 6; it++) {
            int j = it * 1024 + tid * 4;
            int r = j / CDIM, col = j % CDIM;
            *(float4*)&Ws[r][col] = *(const float4*)&WT[(c0 + r) * CDIM + col];
        }
        // stage X chunk: 32x128 floats, coalesced
#pragma unroll
        for (int it = 0; it < 4; it++) {
            int j = it * 1024 + tid * 4;
            int r = j >> 7, col = j & 127;
            *(float4*)&Xs[r][col] = *(const float4*)&inb[(size_t)(c0 + r) * HWP + p0 + col];
        }
        __syncthreads();
#pragma unroll 4
        for (int k = 0; k < 32; k++) {
            float xv[4];
            *(float4*)xv = *(float4*)&Xs[k][tp * 4];
            float wv[24];
#pragma unroll
            for (int m = 0; m < 24; m += 4) *(float4*)&wv[m] = *(float4*)&Ws[k][to * 24 + m];
#pragma unroll
            for (int m = 0; m < 24; m++)
#pragma unroll
                for (int q = 0; q < 4; q++) acc[m][q] = fmaf(wv[m], xv[q], acc[m][q]);
        }
        __syncthreads();
    }
    float* outb = out + (size_t)b * CDIM * HWP;
#pragma unroll
    for (int m = 0; m < 24; m++) {
        int o = to * 24 + m;
        *(float4*)&outb[(size_t)o * HWP + p0 + tp * 4] = *(float4*)&acc[m][0];
    }
}

extern "C" void kernel_launch(void* const* d_in, const int* in_sizes, int n_in,
                              void* d_out, int out_size, void* d_ws, size_t ws_size,
                              hipStream_t stream) {
    const float* x  = (const float*)d_in[0];
    const float* Wk = (const float*)d_in[1];
    const float* bk = (const float*)d_in[2];
    const float* Wg = (const float*)d_in[3];
    const float* bg = (const float*)d_in[4];
    const float* Wx = (const float*)d_in[5];
    const float* bx = (const float*)d_in[6];
    const float* Wp = (const float*)d_in[7];
    const float* bp = (const float*)d_in[8];
    const float* dc = (const float*)d_in[9];
    float* out = (float*)d_out;

    char* ws = (char*)d_ws;
    // workspace layout (bytes)
    size_t off_WxT = 0;                              // 36864 floats
    size_t off_WpT = off_WxT + 36864 * 4;            // 36864 floats
    size_t off_px  = off_WpT + 36864 * 4;            // 27648 floats
    size_t off_kk  = off_px + 27648 * 4;             // 27648 floats
    size_t off_xp  = off_kk + 27648 * 4;             // B*C*HWP floats
    size_t xp_bytes = (size_t)BDIM * CDIM * HWP * 4;
    size_t off_y   = off_xp + xp_bytes;

    float* WxT = (float*)(ws + off_WxT);
    float* WpT = (float*)(ws + off_WpT);
    float* px  = (float*)(ws + off_px);
    float* kkp = (float*)(ws + off_kk);
    float* xp  = (float*)(ws + off_xp);
    // y goes in ws if it fits, else reuse d_out (conv192 is in-place safe)
    float* y = (ws_size >= off_y + xp_bytes) ? (float*)(ws + off_y) : out;

    transpose192_kernel<<<dim3(288), dim3(256), 0, stream>>>(Wx, Wp, WxT, WpT);
    pool9_kernel<<<dim3(BDIM * CDIM * 9), dim3(256), 0, stream>>>(x, px);
    make_kernels_kernel<<<dim3(BDIM), dim3(CDIM), 0, stream>>>(px, Wk, bk, Wg, bg, dc, kkp);
    conv192_kernel<<<dim3(HWP / CONV_N, BDIM), dim3(256), 0, stream>>>(x, WxT, bx, xp);
    dwconv_kernel<<<dim3(BDIM * CDIM * HWP / 256), dim3(256), 0, stream>>>(xp, kkp, y);
    conv192_kernel<<<dim3(HWP / CONV_N, BDIM), dim3(256), 0, stream>>>(y, WpT, bp, out);
}

// Round 2
// 582.792 us; speedup vs baseline: 1.2004x; 1.2004x over previous
//
#include <hip/hip_runtime.h>
#include <math.h>

#define CDIM 192
#define HWP 9216      // 96*96
#define WIMG 96
#define HIMG 96
#define BDIM 16
#define CONV_N 128

// ---------------- pool: px[b,c,j] = mean over 1024 contiguous floats ----------------
__global__ void pool9_kernel(const float* __restrict__ x, float* __restrict__ px) {
    int blk = blockIdx.x;                          // b*C*9 + c*9 + j
    const float* base = x + (size_t)(blk / 9) * HWP + (size_t)(blk % 9) * 1024;
    float4 v = ((const float4*)base)[threadIdx.x]; // 256 threads * 4 floats = 1024
    float s = v.x + v.y + v.z + v.w;
#pragma unroll
    for (int off = 32; off > 0; off >>= 1) s += __shfl_down(s, off, 64);
    __shared__ float ls[4];
    int wid = threadIdx.x >> 6;
    if ((threadIdx.x & 63) == 0) ls[wid] = s;
    __syncthreads();
    if (threadIdx.x == 0) px[blk] = (ls[0] + ls[1] + ls[2] + ls[3]) * (1.0f / 1024.0f);
}

// ---------------- small: build per-(b,c) 3x3 kernels ----------------
__global__ void make_kernels_kernel(const float* __restrict__ px,
                                    const float* __restrict__ Wk, const float* __restrict__ bk,
                                    const float* __restrict__ Wg, const float* __restrict__ bg,
                                    const float* __restrict__ dc,
                                    float* __restrict__ kk) {
    int b = blockIdx.x;
    int o = threadIdx.x;  // 0..191
    __shared__ float pxs[CDIM * 9];
    for (int i = threadIdx.x; i < CDIM * 9; i += blockDim.x) pxs[i] = px[b * CDIM * 9 + i];
    __syncthreads();
    float k1[9];
    float bias = bk[o];
#pragma unroll
    for (int j = 0; j < 9; j++) k1[j] = bias;
    for (int c = 0; c < CDIM; c++) {
        float w = Wk[o * CDIM + c];
#pragma unroll
        for (int j = 0; j < 9; j++) k1[j] = fmaf(w, pxs[c * 9 + j], k1[j]);
    }
#pragma unroll
    for (int j = 0; j < 9; j++) {
        float v = k1[j];
        k1[j] = 0.5f * v * (1.0f + erff(v * 0.70710678118654752f));  // exact GELU
    }
    float k2[9];
    float mean = 0.f;
#pragma unroll
    for (int i = 0; i < 9; i++) {
        float a = bg[i];
#pragma unroll
        for (int j = 0; j < 9; j++) a = fmaf(k1[j], Wg[i * 9 + j], a);
        k2[i] = a;
        mean += a;
    }
    mean *= (1.0f / 9.0f);
    float f = 1.0f / (1.0f + expf(-dc[o]));
    float sub = f * mean;
#pragma unroll
    for (int i = 0; i < 9; i++) kk[(b * CDIM + o) * 9 + i] = k2[i] - sub;
}

// ---------------- transpose the two 192x192 weight mats: WT[c][o] = W[o][c] ----------------
__global__ void transpose192_kernel(const float* __restrict__ A, const float* __restrict__ Bm,
                                    float* __restrict__ AT, float* __restrict__ BT) {
    int i = blockIdx.x * 256 + threadIdx.x;  // 0 .. 2*36864-1
    int m = i / (CDIM * CDIM);
    int idx = i % (CDIM * CDIM);
    int c = idx / CDIM, o = idx % CDIM;
    const float* src = m ? Bm : A;
    float* dst = m ? BT : AT;
    dst[idx] = src[o * CDIM + c];
}

// ---------------- depthwise 3x3 via LDS half-image tiles ----------------
// Block = (bc, half). Owns output rows [half*48, half*48+48) of one (b,c) plane.
// LDS tile: 50 rows (incl. +-1 halo) x 100 cols (96 data + zero ring), front pad 4
// so that S[-1] (left halo of col 0 == previous row col 99 == zero) is in-bounds.
#define SROW 100
__global__ __launch_bounds__(256) void dwconv_lds_kernel(const float* __restrict__ xp,
                                                         const float* __restrict__ kk,
                                                         float* __restrict__ y) {
    int bc = blockIdx.x >> 1;
    int row0 = (blockIdx.x & 1) * 48;
    int tid = threadIdx.x;

    __shared__ __align__(16) float Sbuf[4 + 50 * SROW + 4];
    float* S = Sbuf + 4;

    float kv[9];
#pragma unroll
    for (int j = 0; j < 9; j++) kv[j] = kk[bc * 9 + j];

    // zero everything (halo ring must be 0)
    float4 z4 = make_float4(0.f, 0.f, 0.f, 0.f);
    for (int i = tid; i < (4 + 50 * SROW + 4) / 4; i += 256) ((float4*)Sbuf)[i] = z4;
    __syncthreads();

    // load interior: S row s <- img row (row0-1+s), cols 0..95
    const float* src = xp + (size_t)bc * HWP;
    for (int i = tid; i < 50 * 24; i += 256) {
        int s = i / 24, j4 = i % 24;
        int hh = row0 - 1 + s;
        if (hh >= 0 && hh < HIMG) {
            float4 v = *(const float4*)(src + (size_t)hh * WIMG + 4 * j4);
            *(float4*)&S[s * SROW + 4 * j4] = v;
        }
    }
    __syncthreads();

    // compute: 48 rows x 24 groups of 4 outputs
    float* dst = y + (size_t)bc * HWP;
    for (int i = tid; i < 48 * 24; i += 256) {
        int h = i / 24, wg = i % 24;
        float a0 = 0.f, a1 = 0.f, a2 = 0.f, a3 = 0.f;
#pragma unroll
        for (int r = 0; r < 3; r++) {
            const float* row = &S[(h + r) * SROW + 4 * wg];
            float left = row[-1];
            float4 m = *(const float4*)row;
            float r4 = row[4];
            float c0 = kv[r * 3 + 0], c1 = kv[r * 3 + 1], c2 = kv[r * 3 + 2];
            a0 = fmaf(c0, left, fmaf(c1, m.x, fmaf(c2, m.y, a0)));
            a1 = fmaf(c0, m.x, fmaf(c1, m.y, fmaf(c2, m.z, a1)));
            a2 = fmaf(c0, m.y, fmaf(c1, m.z, fmaf(c2, m.w, a2)));
            a3 = fmaf(c0, m.z, fmaf(c1, m.w, fmaf(c2, r4, a3)));
        }
        float4 o = make_float4(a0, a1, a2, a3);
        *(float4*)(dst + (size_t)(row0 + h) * WIMG + 4 * wg) = o;
    }
}

// ---------------- conv1x1, K=192, M=192 (all out channels per block), N=128 ----------------
// In-place safe when in==out aliasing at pixel granularity: each block reads ONLY its own
// (b, p0..p0+127) columns (all c) and writes only that range (all o), writes after final barrier.
__global__ __launch_bounds__(256, 2) void conv192_kernel(
    const float* __restrict__ in,   // [B][192][9216]
    const float* __restrict__ WT,   // [192 c][192 o]
    const float* __restrict__ bias, // [192]
    float* __restrict__ out) {      // [B][192][9216]
    int p0 = blockIdx.x * CONV_N;
    int b = blockIdx.y;
    int tid = threadIdx.x;
    int to = tid >> 5;   // 0..7 -> owns o in [to*24, to*24+24)
    int tp = tid & 31;   // 0..31 -> owns p in [p0+tp*4, +4)

    __shared__ float Ws[32][CDIM];    // 24 KB
    __shared__ float Xs[32][CONV_N];  // 16 KB

    float acc[24][4];
#pragma unroll
    for (int m = 0; m < 24; m++) {
        float bv = bias[to * 24 + m];
#pragma unroll
        for (int q = 0; q < 4; q++) acc[m][q] = bv;
    }

    const float* inb = in + (size_t)b * CDIM * HWP;

    for (int ks = 0; ks < 6; ks++) {
        int c0 = ks * 32;
        // stage W chunk: 32x192 floats, coalesced from WT (c-major)
#pragma unroll
        for (int it = 0; it < 6; it++) {
            int j = it * 1024 + tid * 4;
            int r = j / CDIM, col = j % CDIM;
            *(float4*)&Ws[r][col] = *(const float4*)&WT[(c0 + r) * CDIM + col];
        }
        // stage X chunk: 32x128 floats, coalesced
#pragma unroll
        for (int it = 0; it < 4; it++) {
            int j = it * 1024 + tid * 4;
            int r = j >> 7, col = j & 127;
            *(float4*)&Xs[r][col] = *(const float4*)&inb[(size_t)(c0 + r) * HWP + p0 + col];
        }
        __syncthreads();
#pragma unroll 4
        for (int k = 0; k < 32; k++) {
            float xv[4];
            *(float4*)xv = *(float4*)&Xs[k][tp * 4];
            float wv[24];
#pragma unroll
            for (int m = 0; m < 24; m += 4) *(float4*)&wv[m] = *(float4*)&Ws[k][to * 24 + m];
#pragma unroll
            for (int m = 0; m < 24; m++)
#pragma unroll
                for (int q = 0; q < 4; q++) acc[m][q] = fmaf(wv[m], xv[q], acc[m][q]);
        }
        __syncthreads();
    }
    float* outb = out + (size_t)b * CDIM * HWP;
#pragma unroll
    for (int m = 0; m < 24; m++) {
        int o = to * 24 + m;
        *(float4*)&outb[(size_t)o * HWP + p0 + tp * 4] = *(float4*)&acc[m][0];
    }
}

extern "C" void kernel_launch(void* const* d_in, const int* in_sizes, int n_in,
                              void* d_out, int out_size, void* d_ws, size_t ws_size,
                              hipStream_t stream) {
    const float* x  = (const float*)d_in[0];
    const float* Wk = (const float*)d_in[1];
    const float* bk = (const float*)d_in[2];
    const float* Wg = (const float*)d_in[3];
    const float* bg = (const float*)d_in[4];
    const float* Wx = (const float*)d_in[5];
    const float* bx = (const float*)d_in[6];
    const float* Wp = (const float*)d_in[7];
    const float* bp = (const float*)d_in[8];
    const float* dc = (const float*)d_in[9];
    float* out = (float*)d_out;

    char* ws = (char*)d_ws;
    // workspace layout (bytes)
    size_t off_WxT = 0;                              // 36864 floats
    size_t off_WpT = off_WxT + 36864 * 4;            // 36864 floats
    size_t off_px  = off_WpT + 36864 * 4;            // 27648 floats
    size_t off_kk  = off_px + 27648 * 4;             // 27648 floats
    size_t off_xp  = off_kk + 27648 * 4;             // B*C*HWP floats (16B-aligned: 516096)
    size_t xp_bytes = (size_t)BDIM * CDIM * HWP * 4;
    size_t off_y   = off_xp + xp_bytes;

    float* WxT = (float*)(ws + off_WxT);
    float* WpT = (float*)(ws + off_WpT);
    float* px  = (float*)(ws + off_px);
    float* kkp = (float*)(ws + off_kk);
    float* xp  = (float*)(ws + off_xp);
    // y goes in ws if it fits, else reuse d_out (conv192 is in-place safe)
    float* y = (ws_size >= off_y + xp_bytes) ? (float*)(ws + off_y) : out;

    transpose192_kernel<<<dim3(288), dim3(256), 0, stream>>>(Wx, Wp, WxT, WpT);
    pool9_kernel<<<dim3(BDIM * CDIM * 9), dim3(256), 0, stream>>>(x, px);
    make_kernels_kernel<<<dim3(BDIM), dim3(CDIM), 0, stream>>>(px, Wk, bk, Wg, bg, dc, kkp);
    conv192_kernel<<<dim3(HWP / CONV_N, BDIM), dim3(256), 0, stream>>>(x, WxT, bx, xp);
    dwconv_lds_kernel<<<dim3(BDIM * CDIM * 2), dim3(256), 0, stream>>>(xp, kkp, y);
    conv192_kernel<<<dim3(HWP / CONV_N, BDIM), dim3(256), 0, stream>>>(y, WpT, bp, out);
}

// Round 4
// 341.447 us; speedup vs baseline: 2.0488x; 1.7068x over previous
//
#include <hip/hip_runtime.h>
#include <math.h>

#define CDIM 192
#define HWP 9216      // 96*96
#define WIMG 96
#define HIMG 96
#define BDIM 16

typedef float f32x4 __attribute__((ext_vector_type(4)));
typedef short bf16x8 __attribute__((ext_vector_type(8)));

__device__ __forceinline__ ushort f2bf(float f) {
    uint u = __builtin_bit_cast(uint, f);
    u += 0x7FFFu + ((u >> 16) & 1);           // round-to-nearest-even
    return (ushort)(u >> 16);
}
__device__ __forceinline__ float bf2f(ushort h) {
    return __builtin_bit_cast(float, (uint)h << 16);
}

// ---------------- prep: bake W (o-major [192][192] fp32) into MFMA B-fragment order ----------------
// Wf[((ks*12 + nf)*64 + l)*8 + i] = bf16( W[o=nf*16+(l&15)][c = ks*32 + (l>>4)*8 + i] )
// The (g,i)->k mapping is applied identically on the A-side LDS read, so any hw k-permutation cancels.
__global__ void prep_wfrag_kernel(const float* __restrict__ Wx, const float* __restrict__ Wp,
                                  ushort* __restrict__ WxF, ushort* __restrict__ WpF) {
    int t = blockIdx.x * 256 + threadIdx.x;    // 0 .. 9215
    int m = t / 4608;
    int r = t % 4608;                          // ks*768 + nf*64 + l
    int ks = r / 768, nf = (r / 64) % 12, l = r % 64;
    const float* W = m ? Wp : Wx;
    ushort* F = m ? WpF : WxF;
    int o = nf * 16 + (l & 15);
    int c0 = ks * 32 + (l >> 4) * 8;
    float4 a = *(const float4*)&W[o * CDIM + c0];
    float4 b = *(const float4*)&W[o * CDIM + c0 + 4];
    ushort* dst = F + (size_t)r * 8;
    dst[0] = f2bf(a.x); dst[1] = f2bf(a.y); dst[2] = f2bf(a.z); dst[3] = f2bf(a.w);
    dst[4] = f2bf(b.x); dst[5] = f2bf(b.y); dst[6] = f2bf(b.z); dst[7] = f2bf(b.w);
}

// ---------------- MFMA conv1x1: out[o][p] = sum_c W[o][c] in[c][p] + bias[o] ----------------
// Block: 64 pixels x 192 out-ch, 4 waves; wave w owns pixels [p0+16w, +16).
// A-frag (in^T): lane l: m=pixel=(l&15), k = ks*32 + (l>>4)*8 + i  -> one ds_read_b128 from S[p][c].
// B-frag: straight 16B load from pre-baked Wf. D: row=pixel=(l>>4)*4+reg, col=o=(l&15)  [m89].
// In-place safe (in_==out_): block reads only its own pixel columns (staged before barrier),
// writes only those columns after MFMA; LDS holds all inputs before any global write.
template<int IN_BF16, int OUT_BF16, int DO_POOL>
__global__ __launch_bounds__(256, 2) void convmfma_kernel(
    const void* __restrict__ in_, const ushort* __restrict__ Wf,
    const float* __restrict__ bias, void* __restrict__ out_,
    float* __restrict__ px) {
    const int p0 = blockIdx.x * 64;
    const int b = blockIdx.y;
    const int tid = threadIdx.x;
    const int l = tid & 63, w = tid >> 6;
    const size_t inplane = (size_t)CDIM * HWP;

    __shared__ __align__(16) ushort S[64 * 200];  // [p local][c], row stride 200 bf16 = 400 B

    // ---- stage + transpose [192 c][64 p] -> S[p][c] (bf16), 4x4 register sub-blocks ----
#pragma unroll
    for (int it = 0; it < 3; ++it) {
        int u = tid + it * 256;                // 768 units
        int p4 = (u & 15) * 4, c4 = (u >> 4) * 4;
        ushort vv[4][4];
        if (IN_BF16) {
            const ushort* inb = (const ushort*)in_ + (size_t)b * inplane;
#pragma unroll
            for (int r = 0; r < 4; ++r) {
                ushort4 t4 = *(const ushort4*)(inb + (size_t)(c4 + r) * HWP + p0 + p4);
                vv[r][0] = t4.x; vv[r][1] = t4.y; vv[r][2] = t4.z; vv[r][3] = t4.w;
            }
        } else {
            const float* inb = (const float*)in_ + (size_t)b * inplane;
#pragma unroll
            for (int r = 0; r < 4; ++r) {
                float4 t4 = *(const float4*)(inb + (size_t)(c4 + r) * HWP + p0 + p4);
                vv[r][0] = f2bf(t4.x); vv[r][1] = f2bf(t4.y);
                vv[r][2] = f2bf(t4.z); vv[r][3] = f2bf(t4.w);
            }
        }
#pragma unroll
        for (int q = 0; q < 4; ++q) {
            *(ushort4*)&S[(p4 + q) * 200 + c4] =
                make_ushort4(vv[0][q], vv[1][q], vv[2][q], vv[3][q]);
        }
    }
    __syncthreads();

    if (DO_POOL) {
        // partial pool sums: this block covers pixels [p0, p0+64) = 1/16 of segment p0/1024
        if (tid < CDIM) {
            float s = 0.f;
#pragma unroll 8
            for (int p = 0; p < 64; ++p) s += bf2f(S[p * 200 + tid]);
            atomicAdd(&px[(b * CDIM + tid) * 9 + (p0 >> 10)], s);
        }
    }

    f32x4 acc[12];
#pragma unroll
    for (int nf = 0; nf < 12; ++nf) {
        float bv = bias[nf * 16 + (l & 15)];
        acc[nf] = (f32x4){bv, bv, bv, bv};
    }

    const ushort* Sp = &S[(w * 16 + (l & 15)) * 200];
    const int g8 = (l >> 4) * 8;
#pragma unroll
    for (int ks = 0; ks < 6; ++ks) {
        bf16x8 a = *(const bf16x8*)(Sp + ks * 32 + g8);
#pragma unroll
        for (int nf = 0; nf < 12; ++nf) {
            bf16x8 bb = *(const bf16x8*)&Wf[(size_t)((ks * 12 + nf) * 64 + l) * 8];
            acc[nf] = __builtin_amdgcn_mfma_f32_16x16x32_bf16(a, bb, acc[nf], 0, 0, 0);
        }
    }

    const int p_out = p0 + w * 16 + (l >> 4) * 4;   // 4 consecutive pixels per lane
#pragma unroll
    for (int nf = 0; nf < 12; ++nf) {
        int o = nf * 16 + (l & 15);
        if (OUT_BF16) {
            ushort* ob = (ushort*)out_ + (size_t)b * inplane + (size_t)o * HWP + p_out;
            *(ushort4*)ob = make_ushort4(f2bf(acc[nf][0]), f2bf(acc[nf][1]),
                                         f2bf(acc[nf][2]), f2bf(acc[nf][3]));
        } else {
            float* ob = (float*)out_ + (size_t)b * inplane + (size_t)o * HWP + p_out;
            *(float4*)ob = make_float4(acc[nf][0], acc[nf][1], acc[nf][2], acc[nf][3]);
        }
    }
}

// ---------------- small: build per-(b,c) 3x3 kernels (px holds SUMS of 1024 px) ----------------
__global__ void make_kernels_kernel(const float* __restrict__ px,
                                    const float* __restrict__ Wk, const float* __restrict__ bk,
                                    const float* __restrict__ Wg, const float* __restrict__ bg,
                                    const float* __restrict__ dc,
                                    float* __restrict__ kk) {
    int b = blockIdx.x;
    int o = threadIdx.x;  // 0..191
    __shared__ float pxs[CDIM * 9];
    for (int i = threadIdx.x; i < CDIM * 9; i += blockDim.x)
        pxs[i] = px[b * CDIM * 9 + i] * (1.0f / 1024.0f);
    __syncthreads();
    float k1[9];
    float bias = bk[o];
#pragma unroll
    for (int j = 0; j < 9; j++) k1[j] = bias;
    for (int c = 0; c < CDIM; c++) {
        float w = Wk[o * CDIM + c];
#pragma unroll
        for (int j = 0; j < 9; j++) k1[j] = fmaf(w, pxs[c * 9 + j], k1[j]);
    }
#pragma unroll
    for (int j = 0; j < 9; j++) {
        float v = k1[j];
        k1[j] = 0.5f * v * (1.0f + erff(v * 0.70710678118654752f));  // exact GELU
    }
    float k2[9];
    float mean = 0.f;
#pragma unroll
    for (int i = 0; i < 9; i++) {
        float a = bg[i];
#pragma unroll
        for (int j = 0; j < 9; j++) a = fmaf(k1[j], Wg[i * 9 + j], a);
        k2[i] = a;
        mean += a;
    }
    mean *= (1.0f / 9.0f);
    float f = 1.0f / (1.0f + expf(-dc[o]));
    float sub = f * mean;
#pragma unroll
    for (int i = 0; i < 9; i++) kk[(b * CDIM + o) * 9 + i] = k2[i] - sub;
}

// ---------------- depthwise 3x3 via LDS half-image tiles (bf16 in, bf16/f32 out) ----------------
#define SROW 100
template<int OUT_BF16>
__global__ __launch_bounds__(256) void dwconv_kernel_bf16(const ushort* __restrict__ xp,
                                                          const float* __restrict__ kk,
                                                          void* __restrict__ y_) {
    int bc = blockIdx.x >> 1;
    int row0 = (blockIdx.x & 1) * 48;
    int tid = threadIdx.x;

    __shared__ __align__(16) float Sbuf[4 + 50 * SROW + 4];
    float* S = Sbuf + 4;

    float kv[9];
#pragma unroll
    for (int j = 0; j < 9; j++) kv[j] = kk[bc * 9 + j];

    float4 z4 = make_float4(0.f, 0.f, 0.f, 0.f);
    for (int i = tid; i < (4 + 50 * SROW + 4) / 4; i += 256) ((float4*)Sbuf)[i] = z4;
    __syncthreads();

    const ushort* src = xp + (size_t)bc * HWP;
    for (int i = tid; i < 50 * 24; i += 256) {
        int s = i / 24, j4 = i % 24;
        int hh = row0 - 1 + s;
        if (hh >= 0 && hh < HIMG) {
            ushort4 v = *(const ushort4*)(src + (size_t)hh * WIMG + 4 * j4);
            *(float4*)&S[s * SROW + 4 * j4] =
                make_float4(bf2f(v.x), bf2f(v.y), bf2f(v.z), bf2f(v.w));
        }
    }
    __syncthreads();

    for (int i = tid; i < 48 * 24; i += 256) {
        int h = i / 24, wg = i % 24;
        float a0 = 0.f, a1 = 0.f, a2 = 0.f, a3 = 0.f;
#pragma unroll
        for (int r = 0; r < 3; r++) {
            const float* row = &S[(h + r) * SROW + 4 * wg];
            float left = row[-1];
            float4 m = *(const float4*)row;
            float r4 = row[4];
            float c0 = kv[r * 3 + 0], c1 = kv[r * 3 + 1], c2 = kv[r * 3 + 2];
            a0 = fmaf(c0, left, fmaf(c1, m.x, fmaf(c2, m.y, a0)));
            a1 = fmaf(c0, m.x, fmaf(c1, m.y, fmaf(c2, m.z, a1)));
            a2 = fmaf(c0, m.y, fmaf(c1, m.z, fmaf(c2, m.w, a2)));
            a3 = fmaf(c0, m.z, fmaf(c1, m.w, fmaf(c2, r4, a3)));
        }
        if (OUT_BF16) {
            ushort* dst = (ushort*)y_ + (size_t)bc * HWP;
            *(ushort4*)(dst + (size_t)(row0 + h) * WIMG + 4 * wg) =
                make_ushort4(f2bf(a0), f2bf(a1), f2bf(a2), f2bf(a3));
        } else {
            float* dst = (float*)y_ + (size_t)bc * HWP;
            *(float4*)(dst + (size_t)(row0 + h) * WIMG + 4 * wg) =
                make_float4(a0, a1, a2, a3);
        }
    }
}

extern "C" void kernel_launch(void* const* d_in, const int* in_sizes, int n_in,
                              void* d_out, int out_size, void* d_ws, size_t ws_size,
                              hipStream_t stream) {
    const float* x  = (const float*)d_in[0];
    const float* Wk = (const float*)d_in[1];
    const float* bk = (const float*)d_in[2];
    const float* Wg = (const float*)d_in[3];
    const float* bg = (const float*)d_in[4];
    const float* Wx = (const float*)d_in[5];
    const float* bx = (const float*)d_in[6];
    const float* Wp = (const float*)d_in[7];
    const float* bp = (const float*)d_in[8];
    const float* dc = (const float*)d_in[9];
    float* out = (float*)d_out;

    char* ws = (char*)d_ws;
    // layout (bytes); total = 113,614,848 <= ws floor 113,762,304 proven by round-2 pass
    size_t off_WxF = 0;                           // 36864 bf16
    size_t off_WpF = off_WxF + 36864 * 2;
    size_t off_px  = off_WpF + 36864 * 2;         // 27648 f32 (pool SUMS)
    size_t off_kk  = off_px + 27648 * 4;          // 27648 f32
    size_t off_xp  = off_kk + 27648 * 4;          // B*C*HWP bf16
    size_t xp_bytes = (size_t)BDIM * CDIM * HWP * 2;
    size_t off_y   = off_xp + xp_bytes;

    ushort* WxF = (ushort*)(ws + off_WxF);
    ushort* WpF = (ushort*)(ws + off_WpF);
    float*  px  = (float*)(ws + off_px);
    float*  kkp = (float*)(ws + off_kk);
    ushort* xp  = (ushort*)(ws + off_xp);
    bool y_in_ws = (ws_size >= off_y + xp_bytes);

    hipMemsetAsync(px, 0, 27648 * 4, stream);
    prep_wfrag_kernel<<<dim3(36), dim3(256), 0, stream>>>(Wx, Wp, WxF, WpF);
    // conv1: fp32 in, bf16 out, fused pool partial sums
    convmfma_kernel<0, 1, 1><<<dim3(HWP / 64, BDIM), dim3(256), 0, stream>>>(
        (const void*)x, WxF, bx, (void*)xp, px);
    make_kernels_kernel<<<dim3(BDIM), dim3(CDIM), 0, stream>>>(px, Wk, bk, Wg, bg, dc, kkp);

    if (y_in_ws) {
        ushort* y = (ushort*)(ws + off_y);
        dwconv_kernel_bf16<1><<<dim3(BDIM * CDIM * 2), dim3(256), 0, stream>>>(xp, kkp, (void*)y);
        convmfma_kernel<1, 0, 0><<<dim3(HWP / 64, BDIM), dim3(256), 0, stream>>>(
            (const void*)y, WpF, bp, (void*)out, nullptr);
    } else {
        // fallback: y fp32 in d_out, conv2 in-place
        dwconv_kernel_bf16<0><<<dim3(BDIM * CDIM * 2), dim3(256), 0, stream>>>(xp, kkp, (void*)out);
        convmfma_kernel<0, 0, 0><<<dim3(HWP / 64, BDIM), dim3(256), 0, stream>>>(
            (const void*)out, WpF, bp, (void*)out, nullptr);
    }
}